// Round 7
// baseline (478.109 us; speedup 1.0000x reference)
//
#include <hip/hip_runtime.h>

// GeometryTransformation: backproject(theta=0) -> 2x resblock(conv3d 16->16 3^3,
// InstanceNorm, ReLU, residual) -> forward-project at theta in {0, pi/2}.
//
// Round-7: round-6's x-constancy factorization (interior 2D field + width-16
// boundary mini-volume), with the mini conv rebuilt for latency:
//   - B-fragments loaded DIRECTLY from global (16B contiguous in [d][y][x][c])
//     with per-lane predication replacing the LDS halo tile (no barrier, no
//     bank conflicts, 36 independent loads in flight per wave).
//   - wave tile 4y x 16x x 1z -> 1024 mini blocks (16 waves/CU, 2x round-6).
//   - interior conv fused into the same dispatch (blocks 0..127).
// prep/norm/fproj identical to round-6 (passed, absmax 4.0).

typedef unsigned short u16;
typedef unsigned int   u32;
using s16x8 = __attribute__((ext_vector_type(8))) short;
using f32x4 = __attribute__((ext_vector_type(4))) float;

#define IN_ELEMS 262144        // 128*128*16 fp32 interior
#define MN_ELEMS 4194304       // 128*128*16*16 u16 mini
#define WS_NEED  (3ull*IN_ELEMS*4ull + 3ull*MN_ELEMS*2ull + 4096ull)

__device__ __forceinline__ float bf2f(u16 h) {
    union { u32 u; float f; } v; v.u = ((u32)h) << 16; return v.f;
}
__device__ __forceinline__ u16 f2bf(float f) {
    union { float f; u32 u; } v; v.f = f;
    u32 u = v.u;
    return (u16)((u + 0x7fffu + ((u >> 16) & 1u)) >> 16);
}
__device__ __forceinline__ float ldin(const void* p, int i, int bf) {
    return bf ? bf2f(((const u16*)p)[i]) : ((const float*)p)[i];
}
__device__ __forceinline__ u16 ldbf(const void* p, int i, int bf) {
    return bf ? ((const u16*)p)[i] : f2bf(((const float*)p)[i]);
}
__device__ __forceinline__ void unpack8(uint4 a, float* f) {
    u32 w[4] = {a.x, a.y, a.z, a.w};
#pragma unroll
    for (int i = 0; i < 4; i++) {
        f[2*i]   = bf2f((u16)(w[i] & 0xffff));
        f[2*i+1] = bf2f((u16)(w[i] >> 16));
    }
}

// stats zero + dtype sniff (bf16 vs fp32) from w_a1 bit patterns.
__global__ void init_k(const void* __restrict__ w, float* __restrict__ st,
                       int* __restrict__ flag)
{
    const int tid = threadIdx.x;
    for (int i = tid; i < 256; i += 64) st[i] = 0.f;
    if (tid == 0) {
        const u16* p = (const u16*)w;
        int cnt = 0;
        for (int i = 0; i < 32; i++) {
            int e = (p[2 * i] >> 7) & 0xFF;
            if (e >= 64 && e <= 130) cnt++;
        }
        *flag = (cnt >= 24) ? 1 : 0;
    }
}

__global__ void sentinel_k(u16* __restrict__ out, int n)
{
    int i = blockIdx.x * 256 + threadIdx.x;
    if (i < n) out[i] = 0x4640;
}

// Build layer-0 state: interior fp32 + mini (cols {0..4,7,8..11} = proj).
__global__ __launch_bounds__(256) void prep_k(const void* __restrict__ proj,
                                              const int* __restrict__ flagp,
                                              float* __restrict__ I0,
                                              u16* __restrict__ M0)
{
    const int bf = *flagp;
    const int d = blockIdx.x;
    const int tid = threadIdx.x;
    for (int i = tid; i < 2048; i += 256) {
        int y = i >> 4, c = i & 15;
        I0[(d * 128 + y) * 16 + c] = ldin(proj, c * 16384 + d * 128 + y, bf);
    }
    for (int i = tid; i < 4096; i += 256) {
        int y = i >> 5, x = (i >> 1) & 15, hh = i & 1;
        bool on = (x <= 4) | (x == 7) | (x >= 8 && x < 12);
        u32 pw[4] = {0u, 0u, 0u, 0u};
        if (on) {
#pragma unroll
            for (int j = 0; j < 4; j++) {
                int c0 = hh * 8 + 2 * j;
                u16 a = f2bf(ldin(proj, c0 * 16384 + d * 128 + y, bf));
                u16 b = f2bf(ldin(proj, (c0 + 1) * 16384 + d * 128 + y, bf));
                pw[j] = (u32)a | ((u32)b << 16);
            }
        }
        *(uint4*)(M0 + ((d * 128 + y) << 8) + (x << 4) + hh * 8) =
            make_uint4(pw[0], pw[1], pw[2], pw[3]);
    }
}

// ---------------------------------------------------------------------------
// Fused layer: blocks 0..127 = interior 2D conv (kx-summed weights, 120x stats);
// blocks 128..1151 = mini MFMA conv, B-frags direct from global, wave = 4y x 1z.
// Both write raw conv+bias outputs and atomically accumulate stat sums.
// ---------------------------------------------------------------------------
__global__ __launch_bounds__(256) void layer_k(
    const float* __restrict__ Iin,   // normalized interior [d][y][c] fp32
    const u16*  __restrict__ Min,    // normalized mini [d][y][x16][c] bf16
    const void* __restrict__ wgt, const void* __restrict__ bias,
    const int*  __restrict__ flagp,
    float* __restrict__ Iout, u16* __restrict__ Mout,
    float* __restrict__ st_out)
{
    __shared__ float smem[8880];     // 35.5 KB: wsum 2304 | pin 6528 | bl 16 | sred 32
    float* wsum = smem;
    float* pin  = smem + 2304;
    float* bl   = smem + 8832;
    float* sred = smem + 8848;
    const int bf = *flagp;
    const int tid = threadIdx.x;

    if (blockIdx.x < 128) {
        // ---------------- interior path (r6 convI, verbatim logic) ----------
        const int d = blockIdx.x;
        for (int i = tid; i < 2304; i += 256) {
            int co = i & 15, ci = (i >> 4) & 15, kk = i >> 8;
            int kz = kk / 3, ky = kk % 3;
            float s = 0.f;
#pragma unroll
            for (int kx = 0; kx < 3; kx++)
                s += ldin(wgt, (co * 16 + ci) * 27 + kz * 9 + ky * 3 + kx, bf);
            wsum[i] = s;
        }
        if (tid < 16) bl[tid] = ldin(bias, tid, bf);
        if (tid < 32) sred[tid] = 0.f;
        for (int i = tid; i < 6144; i += 256) {
            int p = i >> 11, r = i & 2047, y = r >> 4, c = r & 15;
            int zz = d + p - 1;
            float v = 0.f;
            if ((unsigned)zz < 128u) v = Iin[(zz * 128 + y) * 16 + c];
            pin[p * 2176 + y * 17 + c] = v;
        }
        __syncthreads();

        const int y = tid & 127, h = tid >> 7;
        float acc[8];
#pragma unroll
        for (int cc = 0; cc < 8; cc++) acc[cc] = bl[h * 8 + cc];
#pragma unroll
        for (int kz = 0; kz < 3; kz++) {
#pragma unroll
            for (int ky = 0; ky < 3; ky++) {
                int yy = y + ky - 1;
                if ((unsigned)yy < 128u) {
                    const float* prow = &pin[kz * 2176 + yy * 17];
                    const float* wrow = &wsum[(kz * 3 + ky) * 256 + h * 8];
#pragma unroll
                    for (int ci = 0; ci < 16; ci++) {
                        float v = prow[ci];
#pragma unroll
                        for (int cc = 0; cc < 8; cc++)
                            acc[cc] = fmaf(v, wrow[ci * 16 + cc], acc[cc]);
                    }
                }
            }
        }
        float* op = &Iout[(d * 128 + y) * 16 + h * 8];
        float s[8], q[8];
#pragma unroll
        for (int cc = 0; cc < 8; cc++) {
            op[cc] = acc[cc];
            s[cc] = acc[cc];
            q[cc] = acc[cc] * acc[cc];
        }
#pragma unroll
        for (int off = 1; off < 64; off <<= 1) {
#pragma unroll
            for (int cc = 0; cc < 8; cc++) {
                s[cc] += __shfl_down(s[cc], off, 64);
                q[cc] += __shfl_down(q[cc], off, 64);
            }
        }
        if ((tid & 63) == 0) {
#pragma unroll
            for (int cc = 0; cc < 8; cc++) {
                atomicAdd(&sred[h * 8 + cc], s[cc]);
                atomicAdd(&sred[16 + h * 8 + cc], q[cc]);
            }
        }
        __syncthreads();
        if (tid < 32) atomicAdd(&st_out[tid], 120.f * sred[tid]);
        return;
    }

    // ---------------- mini path: direct-load MFMA conv ----------------------
    const int mb = blockIdx.x - 128;
    const int z  = mb & 127;             // output d-slice
    const int yt = mb >> 7;              // 0..7
    const int l = tid & 63, w = tid >> 6;
    const int n = l & 15, g = l >> 4, h = g & 1, kxs = g >> 1;
    const int y0 = yt * 16 + w * 4;

    if (tid < 32) sred[tid] = 0.f;

    // A-fragments (same mapping as r5/r6, HW-verified)
    s16x8 af[3][3][2];
#pragma unroll
    for (int kz = 0; kz < 3; kz++)
#pragma unroll
        for (int ky = 0; ky < 3; ky++)
#pragma unroll
            for (int grp = 0; grp < 2; grp++) {
                int kx = grp * 2 + kxs;
                s16x8 a;
#pragma unroll
                for (int e = 0; e < 8; e++) {
                    int ci = h * 8 + e;
                    u16 wv = 0;
                    if (kx <= 2)
                        wv = ldbf(wgt, n * 432 + ci * 27 + kz * 9 + ky * 3 + kx, bf);
                    a[e] = (short)wv;
                }
                af[kz][ky][grp] = a;
            }
    f32x4 binit;
#pragma unroll
    for (int r = 0; r < 4; r++) binit[r] = ldin(bias, g * 4 + r, bf);

    f32x4 acc[4];
#pragma unroll
    for (int yl = 0; yl < 4; yl++) acc[yl] = binit;

    // B-frag mini-x columns (r6 halo contract: gx in [-1,16], OOB -> 0)
    const int x0 = n + kxs - 1;
    const int x1 = n + kxs + 1;
    const bool v0ok = (unsigned)x0 < 16u;
    const bool v1ok = (unsigned)x1 < 16u;

#pragma unroll
    for (int kz = 0; kz < 3; kz++) {
        const int gz = z + kz - 1;
        const bool zv = (unsigned)gz < 128u;
#pragma unroll
        for (int yin = 0; yin < 6; yin++) {
            const int gy = y0 + yin - 1;
            const bool rv = zv && ((unsigned)gy < 128u);
            const u16* rp = Min + ((((gz << 7) + gy) << 8) + h * 8);
            uint4 q0 = make_uint4(0u, 0u, 0u, 0u);
            uint4 q1 = make_uint4(0u, 0u, 0u, 0u);
            if (rv && v0ok) q0 = *(const uint4*)(rp + (x0 << 4));
            if (rv && v1ok) q1 = *(const uint4*)(rp + (x1 << 4));
            s16x8 f0 = __builtin_bit_cast(s16x8, q0);
            s16x8 f1 = __builtin_bit_cast(s16x8, q1);
#pragma unroll
            for (int ky = 0; ky < 3; ky++) {
                const int yl = yin - ky;
                if (yl >= 0 && yl < 4) {
                    acc[yl] = __builtin_amdgcn_mfma_f32_16x16x32_bf16(af[kz][ky][0], f0, acc[yl], 0, 0, 0);
                    acc[yl] = __builtin_amdgcn_mfma_f32_16x16x32_bf16(af[kz][ky][1], f1, acc[yl], 0, 0, 0);
                }
            }
        }
    }

    // epilogue: D col=lane&15 -> mini x, row=g*4+r -> co. Stats from real cols.
    const float inc = (((n >> 2) & 1) == 0) ? 1.f : 0.f;
    float sr[4] = {0.f, 0.f, 0.f, 0.f}, qr[4] = {0.f, 0.f, 0.f, 0.f};
#pragma unroll
    for (int yl = 0; yl < 4; yl++) {
        const int gy = y0 + yl;
        u32 lo = (u32)f2bf(acc[yl][0]) | ((u32)f2bf(acc[yl][1]) << 16);
        u32 hi = (u32)f2bf(acc[yl][2]) | ((u32)f2bf(acc[yl][3]) << 16);
        *(uint2*)(Mout + (((z << 7) + gy) << 8) + (n << 4) + g * 4) = make_uint2(lo, hi);
#pragma unroll
        for (int r = 0; r < 4; r++) {
            sr[r] += inc * acc[yl][r];
            qr[r] = fmaf(inc * acc[yl][r], acc[yl][r], qr[r]);
        }
    }
#pragma unroll
    for (int off = 1; off < 16; off <<= 1) {
#pragma unroll
        for (int r = 0; r < 4; r++) {
            sr[r] += __shfl_down(sr[r], off, 16);
            qr[r] += __shfl_down(qr[r], off, 16);
        }
    }
    __syncthreads();   // sred zeroing visible to all waves
    if (n == 0) {
#pragma unroll
        for (int r = 0; r < 4; r++) {
            atomicAdd(&sred[g * 4 + r], sr[r]);
            atomicAdd(&sred[16 + g * 4 + r], qr[r]);
        }
    }
    __syncthreads();
    if (tid < 32) atomicAdd(&st_out[tid], sred[tid]);
}

// Normalize layer (r6 verbatim): m,s from raw sums; RES adds vol0(=proj).
// Rebuilds interior fp32 + mini bf16 (ghost cols 4/7 = interior, rest zeroed).
template <int RES>
__global__ __launch_bounds__(256) void norm_k(
    const float* __restrict__ Iraw, const u16* __restrict__ Mraw,
    const void* __restrict__ proj, const float* __restrict__ stL,
    const int* __restrict__ flagp,
    float* __restrict__ Iout, u16* __restrict__ Mout)
{
    __shared__ float sA[32];
    const int bf = *flagp;
    const int d = blockIdx.x;
    const int tid = threadIdx.x;
    if (tid < 32) {
        const float inv = 1.f / 2097152.f;
        int c = tid & 15;
        float m = stL[c] * inv;
        if (tid < 16) sA[tid] = m;
        else          sA[tid] = rsqrtf(stL[16 + c] * inv - m * m + 1e-5f);
    }
    __syncthreads();
    for (int i = tid; i < 2048; i += 256) {
        int y = i >> 4, c = i & 15;
        float res = RES ? ldin(proj, c * 16384 + d * 128 + y, bf) : 0.f;
        float v = fmaxf((Iraw[(d * 128 + y) * 16 + c] - sA[c]) * sA[16 + c] + res, 0.f);
        Iout[(d * 128 + y) * 16 + c] = v;
    }
    for (int i = tid; i < 4096; i += 256) {
        int y = i >> 5, x = (i >> 1) & 15, hh = i & 1;
        bool realc = (x < 4) | (x >= 8 && x < 12);
        bool ghost = (x == 4) | (x == 7);
        u32 pw[4] = {0u, 0u, 0u, 0u};
        if (realc | ghost) {
            float f[8];
            if (realc) {
                uint4 raw = *(const uint4*)(Mraw + ((d * 128 + y) << 8) + (x << 4) + hh * 8);
                unpack8(raw, f);
            } else {
#pragma unroll
                for (int j = 0; j < 8; j++)
                    f[j] = Iraw[(d * 128 + y) * 16 + hh * 8 + j];
            }
            float vals[8];
#pragma unroll
            for (int j = 0; j < 8; j++) {
                int c = hh * 8 + j;
                float res = RES ? ldin(proj, c * 16384 + d * 128 + y, bf) : 0.f;
                vals[j] = fmaxf((f[j] - sA[c]) * sA[16 + c] + res, 0.f);
            }
#pragma unroll
            for (int j = 0; j < 4; j++)
                pw[j] = (u32)f2bf(vals[2*j]) | ((u32)f2bf(vals[2*j+1]) << 16);
        }
        *(uint4*)(Mout + ((d * 128 + y) << 8) + (x << 4) + hh * 8) =
            make_uint4(pw[0], pw[1], pw[2], pw[3]);
    }
}

// Final projection (r6 verbatim): vol2 = relu((y4-m)s + xb); row sums = 120*v2d
// + 8 cols; col sums: interior share Sum_y v2d; i==0 sums y<64 only.
__global__ __launch_bounds__(256) void fproj_k(
    const float* __restrict__ I4, const float* __restrict__ IXB,
    const u16* __restrict__ M4, const u16* __restrict__ MXB,
    const float* __restrict__ stL, const int* __restrict__ flagp,
    void* __restrict__ out)
{
    __shared__ float v2b[128 * 129];
    __shared__ float v2d[16 * 129];
    __shared__ float colsum[128], Ssum[16], C0[16];
    __shared__ float sA[32];
    const int bf = *flagp;
    const int d = blockIdx.x;
    const int tid = threadIdx.x;
    if (tid < 32) {
        const float inv = 1.f / 2097152.f;
        int c = tid & 15;
        float m = stL[c] * inv;
        if (tid < 16) sA[tid] = m;
        else          sA[tid] = rsqrtf(stL[16 + c] * inv - m * m + 1e-5f);
    }
    __syncthreads();

    const int y = tid & 127, h = tid >> 7;
#pragma unroll
    for (int cc = 0; cc < 8; cc++) {
        int c = h * 8 + cc;
        int e = (d * 128 + y) * 16 + c;
        float v = fmaxf((I4[e] - sA[c]) * sA[16 + c] + IXB[e], 0.f);
        v2d[c * 129 + y] = v;
    }
#pragma unroll
    for (int j = 0; j < 8; j++) {
        int x = (j < 4) ? j : j + 4;
        int e = ((d * 128 + y) << 8) + (x << 4) + h * 8;
        float f4[8], fx[8];
        unpack8(*(const uint4*)(M4 + e), f4);
        unpack8(*(const uint4*)(MXB + e), fx);
#pragma unroll
        for (int cc = 0; cc < 8; cc++) {
            int c = h * 8 + cc;
            float v = fmaxf((f4[cc] - sA[c]) * sA[16 + c] + fx[cc], 0.f);
            v2b[(j * 16 + c) * 129 + y] = v;
        }
    }
    __syncthreads();

    {
        float row[8];
#pragma unroll
        for (int cc = 0; cc < 8; cc++) row[cc] = 120.f * v2d[(h * 8 + cc) * 129 + y];
#pragma unroll
        for (int j = 0; j < 8; j++)
#pragma unroll
            for (int cc = 0; cc < 8; cc++)
                row[cc] += v2b[(j * 16 + h * 8 + cc) * 129 + y];
#pragma unroll
        for (int cc = 0; cc < 8; cc++) {
            int c = h * 8 + cc;
            int oi = (c * 2 + 0) * 16384 + d * 128 + y;
            if (bf) ((u16*)out)[oi] = f2bf(row[cc]); else ((float*)out)[oi] = row[cc];
        }
    }

    if (tid < 128) {
        int j = tid >> 4, c = tid & 15;
        float s = 0.f, s0 = 0.f;
        for (int yy = 0; yy < 128; yy++) {
            float v = v2b[(j * 16 + c) * 129 + yy];
            s += v;
            if (yy < 64) s0 += v;
        }
        colsum[j * 16 + c] = s;
        if (j == 0) C0[c] = s0;
    } else if (tid < 144) {
        int c = tid - 128;
        float s = 0.f;
        for (int yy = 0; yy < 128; yy++) s += v2d[c * 129 + yy];
        Ssum[c] = s;
    }
    __syncthreads();

    for (int i = tid; i < 2048; i += 256) {
        int c = i >> 7, u = i & 127;
        float v;
        if (u == 0)        v = C0[c];
        else if (u < 4)    v = colsum[u * 16 + c];
        else if (u >= 124) v = colsum[(u - 120) * 16 + c];
        else               v = Ssum[c];
        int oi = (c * 2 + 1) * 16384 + d * 128 + u;
        if (bf) ((u16*)out)[oi] = f2bf(v); else ((float*)out)[oi] = v;
    }
}

extern "C" void kernel_launch(void* const* d_in, const int* in_sizes, int n_in,
                              void* d_out, int out_size, void* d_ws, size_t ws_size,
                              hipStream_t stream)
{
    if (ws_size < WS_NEED) {
        sentinel_k<<<(out_size + 255) / 256, 256, 0, stream>>>((u16*)d_out, out_size);
        return;
    }
    const void* proj = d_in[0];
    const void* w1 = d_in[1]; const void* b1 = d_in[2];
    const void* w2 = d_in[3]; const void* b2 = d_in[4];
    const void* w3 = d_in[5]; const void* b3 = d_in[6];
    const void* w4 = d_in[7]; const void* b4 = d_in[8];

    float* I_A  = (float*)d_ws;
    float* I_B  = I_A + IN_ELEMS;
    float* I_XB = I_B + IN_ELEMS;
    u16*   M_A  = (u16*)(I_XB + IN_ELEMS);
    u16*   M_B  = M_A + MN_ELEMS;
    u16*   M_XB = M_B + MN_ELEMS;
    float* st   = (float*)(M_XB + MN_ELEMS);
    int*   flag = (int*)(st + 256);

    init_k<<<1, 64, 0, stream>>>(w1, st, flag);
    prep_k<<<128, 256, 0, stream>>>(proj, flag, I_A, M_A);

    dim3 lg(1152), cb(256);
    // L1
    layer_k<<<lg, cb, 0, stream>>>(I_A, M_A, w1, b1, flag, I_B, M_B, st + 0);
    norm_k<0><<<128, cb, 0, stream>>>(I_B, M_B, proj, st + 0, flag, I_A, M_A);     // n1
    // L2
    layer_k<<<lg, cb, 0, stream>>>(I_A, M_A, w2, b2, flag, I_B, M_B, st + 64);
    norm_k<1><<<128, cb, 0, stream>>>(I_B, M_B, proj, st + 64, flag, I_XB, M_XB);  // xb
    // L3
    layer_k<<<lg, cb, 0, stream>>>(I_XB, M_XB, w3, b3, flag, I_B, M_B, st + 128);
    norm_k<0><<<128, cb, 0, stream>>>(I_B, M_B, proj, st + 128, flag, I_A, M_A);   // n3
    // L4
    layer_k<<<lg, cb, 0, stream>>>(I_A, M_A, w4, b4, flag, I_B, M_B, st + 192);
    // final projection
    fproj_k<<<128, cb, 0, stream>>>(I_B, I_XB, M_B, M_XB, st + 192, flag, d_out);
}

// Round 8
// 233.721 us; speedup vs baseline: 2.0456x; 2.0456x over previous
//
#include <hip/hip_runtime.h>

// GeometryTransformation: backproject(theta=0) -> 2x resblock(conv3d 16->16 3^3,
// InstanceNorm, ReLU, residual) -> forward-project at theta in {0, pi/2}.
//
// Round-8: r6/r7 x-constancy factorization (interior 2D field + width-16 mini
// boundary volume), rebuilt so hot waves issue only coalesced 16B loads:
//   wprep_k: dtype sniff + stats zero + per-LANE MFMA A-fragments (afrag),
//            kx-summed 2D weights (f32), bias (f32), fproj partial zeroing.
//   prep_k:  layer-0 state (512 blocks).
//   layer_k: blocks 0..255 interior 2D conv (22.8KB LDS, 2 blocks/d);
//            blocks 256..1279 mini MFMA conv (128B LDS, A-frags = 18 coalesced
//            dwordx4, B-frags direct-global predicated). Fused IN stats.
//   norm_k:  512 blocks streaming normalize (+residual), rebuilds ghosts.
//   fproj1_k/fproj2_k: row sums direct + column partial sums via atomics into
//            pre-zeroed ws, then tiny expansion kernel. i==0 col sums y<64 only.
// Math identical to rounds 6/7 (passed, absmax 4.0).

typedef unsigned short u16;
typedef unsigned int   u32;
using s16x8 = __attribute__((ext_vector_type(8))) short;
using f32x4 = __attribute__((ext_vector_type(4))) float;

#define IN_ELEMS 262144        // 128*128*16 fp32 interior
#define MN_ELEMS 4194304       // 128*128*16*16 u16 mini
#define WS_NEED  28505408ull

__device__ __forceinline__ float bf2f(u16 h) {
    union { u32 u; float f; } v; v.u = ((u32)h) << 16; return v.f;
}
__device__ __forceinline__ u16 f2bf(float f) {
    union { float f; u32 u; } v; v.f = f;
    u32 u = v.u;
    return (u16)((u + 0x7fffu + ((u >> 16) & 1u)) >> 16);
}
__device__ __forceinline__ float ldin(const void* p, int i, int bf) {
    return bf ? bf2f(((const u16*)p)[i]) : ((const float*)p)[i];
}
__device__ __forceinline__ u16 ldbf(const void* p, int i, int bf) {
    return bf ? ((const u16*)p)[i] : f2bf(((const float*)p)[i]);
}
__device__ __forceinline__ void unpack8(uint4 a, float* f) {
    u32 w[4] = {a.x, a.y, a.z, a.w};
#pragma unroll
    for (int i = 0; i < 4; i++) {
        f[2*i]   = bf2f((u16)(w[i] & 0xffff));
        f[2*i+1] = bf2f((u16)(w[i] >> 16));
    }
}
__device__ __forceinline__ void unpack4(uint2 a, float* f) {
    f[0] = bf2f((u16)(a.x & 0xffff)); f[1] = bf2f((u16)(a.x >> 16));
    f[2] = bf2f((u16)(a.y & 0xffff)); f[3] = bf2f((u16)(a.y >> 16));
}

__global__ void sentinel_k(u16* __restrict__ out, int n)
{
    int i = blockIdx.x * 256 + threadIdx.x;
    if (i < n) out[i] = 0x4640;
}

// ---------------------------------------------------------------------------
// One-shot prep of all weight-derived data. 135 blocks:
//  0..17  : afrag[L][fi][lane][8]  (4608 lane-frags, MFMA A operands)
//  18     : st zero + flag + biasf
//  19..98 : zero P/PS/P0 (20480 floats)
//  99..134: w2d[L][tap9][ci][co] kx-summed fp32
// Flag is sniffed locally per block (no cross-block dependency).
// ---------------------------------------------------------------------------
__global__ __launch_bounds__(256) void wprep_k(
    const void* __restrict__ w0, const void* __restrict__ w1,
    const void* __restrict__ w2, const void* __restrict__ w3,
    const void* __restrict__ b0, const void* __restrict__ b1,
    const void* __restrict__ b2, const void* __restrict__ b3,
    float* __restrict__ st, int* __restrict__ flag,
    float* __restrict__ biasf, float* __restrict__ w2d,
    float* __restrict__ pz, u16* __restrict__ afrag)
{
    const int tid = threadIdx.x;
    const u16* pp = (const u16*)w0;
    int cnt = 0;
    for (int i = 0; i < 32; i++) {
        int e = (pp[2 * i] >> 7) & 0xFF;
        if (e >= 64 && e <= 130) cnt++;
    }
    const int bf = (cnt >= 24) ? 1 : 0;
    const void* WS[4] = {w0, w1, w2, w3};
    const void* BS[4] = {b0, b1, b2, b3};
    const int b = blockIdx.x;
    if (b < 18) {
        int gi = b * 256 + tid;               // < 4608
        int L = gi / 1152, r = gi - L * 1152;
        int fi = r >> 6, l = r & 63;
        int kzky = fi >> 1, grp = fi & 1;
        int kz = kzky / 3, ky = kzky % 3;
        int n = l & 15, g = l >> 4, h = g & 1, kxs = g >> 1;
        int kx = grp * 2 + kxs;
        u16 v[8];
#pragma unroll
        for (int e = 0; e < 8; e++) {
            int ci = h * 8 + e;
            v[e] = (kx <= 2) ? ldbf(WS[L], n * 432 + ci * 27 + kz * 9 + ky * 3 + kx, bf)
                             : (u16)0;
        }
#pragma unroll
        for (int e = 0; e < 8; e++) afrag[gi * 8 + e] = v[e];
    } else if (b == 18) {
        st[tid] = 0.f;
        if (tid == 0) *flag = bf;
        if (tid < 64) biasf[tid] = ldin(BS[tid >> 4], tid & 15, bf);
    } else if (b < 99) {
        int i = (b - 19) * 256 + tid;         // < 20480
        pz[i] = 0.f;
    } else {
        int gi = (b - 99) * 256 + tid;        // < 9216
        int L = gi / 2304, r = gi - L * 2304;
        int tap = r >> 8, ci = (r >> 4) & 15, co = r & 15;
        int kz = tap / 3, ky = tap % 3;
        float s = 0.f;
#pragma unroll
        for (int kx = 0; kx < 3; kx++)
            s += ldin(WS[L], (co * 16 + ci) * 27 + kz * 9 + ky * 3 + kx, bf);
        w2d[gi] = s;
    }
}

// Layer-0 state: interior fp32 + mini (cols {0..4,7,8..11} = proj). 512 blocks.
__global__ __launch_bounds__(256) void prep_k(const void* __restrict__ proj,
                                              const int* __restrict__ flagp,
                                              float* __restrict__ I0,
                                              u16* __restrict__ M0)
{
    const int bf = *flagp;
    const int d = blockIdx.x >> 2;
    const int ys = (blockIdx.x & 3) * 32;
    const int tid = threadIdx.x;
    for (int i = tid; i < 512; i += 256) {
        int y = ys + (i >> 4), c = i & 15;
        I0[(d * 128 + y) * 16 + c] = ldin(proj, c * 16384 + d * 128 + y, bf);
    }
    for (int i = tid; i < 1024; i += 256) {
        int y = ys + (i >> 5), x = (i >> 1) & 15, hh = i & 1;
        bool on = (x <= 4) | (x == 7) | (x >= 8 && x < 12);
        u32 pw[4] = {0u, 0u, 0u, 0u};
        if (on) {
#pragma unroll
            for (int j = 0; j < 4; j++) {
                int c0 = hh * 8 + 2 * j;
                u16 a = f2bf(ldin(proj, c0 * 16384 + d * 128 + y, bf));
                u16 b = f2bf(ldin(proj, (c0 + 1) * 16384 + d * 128 + y, bf));
                pw[j] = (u32)a | ((u32)b << 16);
            }
        }
        *(uint4*)(M0 + ((d * 128 + y) << 8) + (x << 4) + hh * 8) =
            make_uint4(pw[0], pw[1], pw[2], pw[3]);
    }
}

// ---------------------------------------------------------------------------
// Fused layer. Blocks 0..255: interior 2D conv, block=(d, y-half of 64).
// Blocks 256..1279: mini MFMA conv (z, yt), wave = 4y. Both accumulate stats.
// ---------------------------------------------------------------------------
__global__ __launch_bounds__(256) void layer_k(
    const float* __restrict__ Iin, const u16* __restrict__ Min,
    const float* __restrict__ w2dL, const u16* __restrict__ afragL,
    const float* __restrict__ biasL,
    float* __restrict__ Iout, u16* __restrict__ Mout,
    float* __restrict__ st_out)
{
    __shared__ float smem[5702];   // interior: wsl 2304 | pin 3366 | sred 32
    const int tid = threadIdx.x;

    if (blockIdx.x < 256) {
        float* wsl  = smem;
        float* pin  = smem + 2304;
        float* sred = smem + 5670;
        const int d  = blockIdx.x >> 1;
        const int y0 = (blockIdx.x & 1) * 64;
        if (tid < 32) sred[tid] = 0.f;
        for (int i = tid; i < 2304; i += 256) wsl[i] = w2dL[i];
        for (int i = tid; i < 3168; i += 256) {
            int p = i / 1056, r = i - p * 1056;
            int row = r >> 4, c = r & 15;
            int zz = d + p - 1, gy = y0 + row - 1;
            float v = 0.f;
            if ((unsigned)zz < 128u && (unsigned)gy < 128u)
                v = Iin[(zz * 128 + gy) * 16 + c];
            pin[p * 1122 + row * 17 + c] = v;
        }
        __syncthreads();

        const int yl = tid & 63, h = tid >> 6;
        float acc[4];
#pragma unroll
        for (int cc = 0; cc < 4; cc++) acc[cc] = biasL[h * 4 + cc];
#pragma unroll
        for (int kz = 0; kz < 3; kz++) {
#pragma unroll
            for (int ky = 0; ky < 3; ky++) {
                const float* rowb = &pin[kz * 1122 + (yl + ky) * 17];
                const float* wrow = &wsl[(kz * 3 + ky) * 256 + h * 4];
#pragma unroll
                for (int ci = 0; ci < 16; ci++) {
                    float v = rowb[ci];
#pragma unroll
                    for (int cc = 0; cc < 4; cc++)
                        acc[cc] = fmaf(v, wrow[ci * 16 + cc], acc[cc]);
                }
            }
        }
        const int e = (d * 128 + y0 + yl) * 16 + h * 4;
        *(float4*)(Iout + e) = make_float4(acc[0], acc[1], acc[2], acc[3]);
        float s[4], q[4];
#pragma unroll
        for (int cc = 0; cc < 4; cc++) { s[cc] = acc[cc]; q[cc] = acc[cc] * acc[cc]; }
#pragma unroll
        for (int off = 1; off < 64; off <<= 1) {
#pragma unroll
            for (int cc = 0; cc < 4; cc++) {
                s[cc] += __shfl_down(s[cc], off, 64);
                q[cc] += __shfl_down(q[cc], off, 64);
            }
        }
        if ((tid & 63) == 0) {
#pragma unroll
            for (int cc = 0; cc < 4; cc++) {
                atomicAdd(&sred[h * 4 + cc], s[cc]);
                atomicAdd(&sred[16 + h * 4 + cc], q[cc]);
            }
        }
        __syncthreads();
        if (tid < 32) atomicAdd(&st_out[tid], 120.f * sred[tid]);
        return;
    }

    // ---------------- mini path ----------------
    float* sred = smem;
    const int mb = blockIdx.x - 256;
    const int z  = mb & 127;
    const int yt = mb >> 7;
    const int l = tid & 63, w = tid >> 6;
    const int n = l & 15, g = l >> 4, h = g & 1, kxs = g >> 1;
    const int y0 = yt * 16 + w * 4;

    if (tid < 32) sred[tid] = 0.f;

    s16x8 af[18];
#pragma unroll
    for (int fi = 0; fi < 18; fi++)
        af[fi] = *(const s16x8*)(afragL + (fi * 64 + l) * 8);
    f32x4 binit = *(const f32x4*)(biasL + g * 4);

    f32x4 acc[4];
#pragma unroll
    for (int yl = 0; yl < 4; yl++) acc[yl] = binit;

    const int x0c = n + kxs - 1;
    const int x1c = x0c + 2;
    const bool v0ok = (unsigned)x0c < 16u;
    const bool v1ok = (unsigned)x1c < 16u;

#pragma unroll
    for (int kz = 0; kz < 3; kz++) {
        const int gz = z + kz - 1;
        const bool zv = (unsigned)gz < 128u;
#pragma unroll
        for (int yin = 0; yin < 6; yin++) {
            const int gy = y0 + yin - 1;
            const bool rv = zv && ((unsigned)gy < 128u);
            const u16* rp = Min + ((((gz << 7) + gy) << 8) + h * 8);
            uint4 q0 = make_uint4(0u, 0u, 0u, 0u);
            uint4 q1 = make_uint4(0u, 0u, 0u, 0u);
            if (rv && v0ok) q0 = *(const uint4*)(rp + (x0c << 4));
            if (rv && v1ok) q1 = *(const uint4*)(rp + (x1c << 4));
            s16x8 f0 = __builtin_bit_cast(s16x8, q0);
            s16x8 f1 = __builtin_bit_cast(s16x8, q1);
#pragma unroll
            for (int ky = 0; ky < 3; ky++) {
                const int yl = yin - ky;
                if (yl >= 0 && yl < 4) {
                    acc[yl] = __builtin_amdgcn_mfma_f32_16x16x32_bf16(af[(kz * 3 + ky) * 2],     f0, acc[yl], 0, 0, 0);
                    acc[yl] = __builtin_amdgcn_mfma_f32_16x16x32_bf16(af[(kz * 3 + ky) * 2 + 1], f1, acc[yl], 0, 0, 0);
                }
            }
        }
    }

    const float inc = (((n >> 2) & 1) == 0) ? 1.f : 0.f;
    float sr[4] = {0.f, 0.f, 0.f, 0.f}, qr[4] = {0.f, 0.f, 0.f, 0.f};
#pragma unroll
    for (int yl = 0; yl < 4; yl++) {
        const int gy = y0 + yl;
        u32 lo = (u32)f2bf(acc[yl][0]) | ((u32)f2bf(acc[yl][1]) << 16);
        u32 hi = (u32)f2bf(acc[yl][2]) | ((u32)f2bf(acc[yl][3]) << 16);
        *(uint2*)(Mout + (((z << 7) + gy) << 8) + (n << 4) + g * 4) = make_uint2(lo, hi);
#pragma unroll
        for (int r = 0; r < 4; r++) {
            sr[r] += inc * acc[yl][r];
            qr[r] = fmaf(inc * acc[yl][r], acc[yl][r], qr[r]);
        }
    }
#pragma unroll
    for (int off = 1; off < 16; off <<= 1) {
#pragma unroll
        for (int r = 0; r < 4; r++) {
            sr[r] += __shfl_down(sr[r], off, 16);
            qr[r] += __shfl_down(qr[r], off, 16);
        }
    }
    __syncthreads();
    if (n == 0) {
#pragma unroll
        for (int r = 0; r < 4; r++) {
            atomicAdd(&sred[g * 4 + r], sr[r]);
            atomicAdd(&sred[16 + g * 4 + r], qr[r]);
        }
    }
    __syncthreads();
    if (tid < 32) atomicAdd(&st_out[tid], sred[tid]);
}

// Streaming normalize (512 blocks): m,s from raw sums; RES adds vol0(=proj).
template <int RES>
__global__ __launch_bounds__(256) void norm_k(
    const float* __restrict__ Iraw, const u16* __restrict__ Mraw,
    const void* __restrict__ proj, const float* __restrict__ stL,
    const int* __restrict__ flagp,
    float* __restrict__ Iout, u16* __restrict__ Mout)
{
    __shared__ float sA[32];
    const int bf = *flagp;
    const int d  = blockIdx.x >> 2;
    const int ys = (blockIdx.x & 3) * 32;
    const int tid = threadIdx.x;
    if (tid < 32) {
        const float inv = 1.f / 2097152.f;
        int c = tid & 15;
        float m = stL[c] * inv;
        sA[tid] = (tid < 16) ? m : rsqrtf(stL[16 + c] * inv - m * m + 1e-5f);
    }
    __syncthreads();
    for (int i = tid; i < 512; i += 256) {
        int y = ys + (i >> 4), c = i & 15;
        float res = RES ? ldin(proj, c * 16384 + d * 128 + y, bf) : 0.f;
        float v = fmaxf((Iraw[(d * 128 + y) * 16 + c] - sA[c]) * sA[16 + c] + res, 0.f);
        Iout[(d * 128 + y) * 16 + c] = v;
    }
    for (int i = tid; i < 1024; i += 256) {
        int y = ys + (i >> 5), x = (i >> 1) & 15, hh = i & 1;
        bool realc = (x < 4) | (x >= 8 && x < 12);
        bool ghost = (x == 4) | (x == 7);
        u32 pw[4] = {0u, 0u, 0u, 0u};
        if (realc | ghost) {
            float f[8];
            if (realc) {
                uint4 raw = *(const uint4*)(Mraw + ((d * 128 + y) << 8) + (x << 4) + hh * 8);
                unpack8(raw, f);
            } else {
#pragma unroll
                for (int j = 0; j < 8; j++)
                    f[j] = Iraw[(d * 128 + y) * 16 + hh * 8 + j];
            }
            float vals[8];
#pragma unroll
            for (int j = 0; j < 8; j++) {
                int c = hh * 8 + j;
                float res = RES ? ldin(proj, c * 16384 + d * 128 + y, bf) : 0.f;
                vals[j] = fmaxf((f[j] - sA[c]) * sA[16 + c] + res, 0.f);
            }
#pragma unroll
            for (int j = 0; j < 4; j++)
                pw[j] = (u32)f2bf(vals[2*j]) | ((u32)f2bf(vals[2*j+1]) << 16);
        }
        *(uint4*)(Mout + ((d * 128 + y) << 8) + (x << 4) + hh * 8) =
            make_uint4(pw[0], pw[1], pw[2], pw[3]);
    }
}

// fproj stage 1: 256 blocks = (d, y-half). vol2 = relu((y4-m)s + xb).
// Writes theta=0 row sums directly; accumulates column partials:
//   P[d][j][c]  (8 mini cols), PS[d][c] (interior Sum_y v2d),
//   P0[d][c] = y<64 partial of col j=0 (written by half-0 only).
__global__ __launch_bounds__(256) void fproj1_k(
    const float* __restrict__ I4, const float* __restrict__ IXB,
    const u16* __restrict__ M4, const u16* __restrict__ MXB,
    const float* __restrict__ stL, const int* __restrict__ flagp,
    void* __restrict__ out,
    float* __restrict__ P, float* __restrict__ PS, float* __restrict__ P0)
{
    __shared__ float sA[32];
    const int bf = *flagp;
    const int d = blockIdx.x >> 1;
    const int half = blockIdx.x & 1;
    const int tid = threadIdx.x;
    if (tid < 32) {
        const float inv = 1.f / 2097152.f;
        int c = tid & 15;
        float m = stL[c] * inv;
        sA[tid] = (tid < 16) ? m : rsqrtf(stL[16 + c] * inv - m * m + 1e-5f);
    }
    __syncthreads();

    const int yl = tid & 63, y = half * 64 + yl;
    const int h = tid >> 6, c0 = h * 4;

    float v2d[4], row[4];
    {
        const int e = (d * 128 + y) * 16 + c0;
        float4 a = *(const float4*)(I4 + e);
        float4 x = *(const float4*)(IXB + e);
        float ia[4] = {a.x, a.y, a.z, a.w};
        float xa[4] = {x.x, x.y, x.z, x.w};
#pragma unroll
        for (int cc = 0; cc < 4; cc++) {
            int c = c0 + cc;
            v2d[cc] = fmaxf((ia[cc] - sA[c]) * sA[16 + c] + xa[cc], 0.f);
            row[cc] = 120.f * v2d[cc];
        }
    }
    float colp[8][4];
#pragma unroll
    for (int j = 0; j < 8; j++) {
        const int m = (j < 4) ? j : j + 4;
        const int e = ((d * 128 + y) << 8) + (m << 4) + c0;
        float f4[4], fx[4];
        unpack4(*(const uint2*)(M4 + e), f4);
        unpack4(*(const uint2*)(MXB + e), fx);
#pragma unroll
        for (int cc = 0; cc < 4; cc++) {
            int c = c0 + cc;
            float v = fmaxf((f4[cc] - sA[c]) * sA[16 + c] + fx[cc], 0.f);
            row[cc] += v;
            colp[j][cc] = v;
        }
    }
#pragma unroll
    for (int cc = 0; cc < 4; cc++) {
        int oi = ((c0 + cc) * 2) * 16384 + d * 128 + y;
        if (bf) ((u16*)out)[oi] = f2bf(row[cc]); else ((float*)out)[oi] = row[cc];
    }
#pragma unroll
    for (int off = 1; off < 64; off <<= 1) {
#pragma unroll
        for (int cc = 0; cc < 4; cc++) {
            v2d[cc] += __shfl_down(v2d[cc], off, 64);
#pragma unroll
            for (int j = 0; j < 8; j++)
                colp[j][cc] += __shfl_down(colp[j][cc], off, 64);
        }
    }
    if (yl == 0) {
#pragma unroll
        for (int cc = 0; cc < 4; cc++) {
            atomicAdd(&PS[d * 16 + c0 + cc], v2d[cc]);
#pragma unroll
            for (int j = 0; j < 8; j++)
                atomicAdd(&P[(d * 8 + j) * 16 + c0 + cc], colp[j][cc]);
            if (half == 0) P0[d * 16 + c0 + cc] = colp[0][cc];
        }
    }
}

// fproj stage 2: expand partials into theta=pi/2 outputs.
__global__ __launch_bounds__(256) void fproj2_k(
    const float* __restrict__ P, const float* __restrict__ PS,
    const float* __restrict__ P0, const int* __restrict__ flagp,
    void* __restrict__ out)
{
    const int bf = *flagp;
    const int d = blockIdx.x;
    const int tid = threadIdx.x;
    for (int i = tid; i < 2048; i += 256) {
        int c = i >> 7, u = i & 127;
        float v;
        if (u == 0)        v = P0[d * 16 + c];
        else if (u < 4)    v = P[(d * 8 + u) * 16 + c];
        else if (u >= 124) v = P[(d * 8 + (u - 120)) * 16 + c];
        else               v = PS[d * 16 + c];
        int oi = (c * 2 + 1) * 16384 + d * 128 + u;
        if (bf) ((u16*)out)[oi] = f2bf(v); else ((float*)out)[oi] = v;
    }
}

extern "C" void kernel_launch(void* const* d_in, const int* in_sizes, int n_in,
                              void* d_out, int out_size, void* d_ws, size_t ws_size,
                              hipStream_t stream)
{
    if (ws_size < WS_NEED) {
        sentinel_k<<<(out_size + 255) / 256, 256, 0, stream>>>((u16*)d_out, out_size);
        return;
    }
    const void* proj = d_in[0];
    const void* w1 = d_in[1]; const void* b1 = d_in[2];
    const void* w2 = d_in[3]; const void* b2 = d_in[4];
    const void* w3 = d_in[5]; const void* b3 = d_in[6];
    const void* w4 = d_in[7]; const void* b4 = d_in[8];

    float* I_A  = (float*)d_ws;
    float* I_B  = I_A + IN_ELEMS;
    float* I_XB = I_B + IN_ELEMS;
    u16*   M_A  = (u16*)(I_XB + IN_ELEMS);
    u16*   M_B  = M_A + MN_ELEMS;
    u16*   M_XB = M_B + MN_ELEMS;
    float* st    = (float*)(M_XB + MN_ELEMS);   // 256
    int*   flag  = (int*)(st + 256);            // 16
    float* biasf = (float*)(flag + 16);         // 64
    float* w2d   = biasf + 64;                  // 9216
    float* P     = w2d + 9216;                  // 16384
    float* PS    = P + 16384;                   // 2048
    float* P0    = PS + 2048;                   // 2048
    u16*   afrag = (u16*)(P0 + 2048);           // 36864

    wprep_k<<<135, 256, 0, stream>>>(w1, w2, w3, w4, b1, b2, b3, b4,
                                     st, flag, biasf, w2d, P, afrag);
    prep_k<<<512, 256, 0, stream>>>(proj, flag, I_A, M_A);

    dim3 lg(1280), cb(256);
    // L1
    layer_k<<<lg, cb, 0, stream>>>(I_A, M_A, w2d + 0,    afrag + 0,     biasf + 0,  I_B, M_B, st + 0);
    norm_k<0><<<512, cb, 0, stream>>>(I_B, M_B, proj, st + 0, flag, I_A, M_A);
    // L2
    layer_k<<<lg, cb, 0, stream>>>(I_A, M_A, w2d + 2304, afrag + 9216,  biasf + 16, I_B, M_B, st + 64);
    norm_k<1><<<512, cb, 0, stream>>>(I_B, M_B, proj, st + 64, flag, I_XB, M_XB);
    // L3
    layer_k<<<lg, cb, 0, stream>>>(I_XB, M_XB, w2d + 4608, afrag + 18432, biasf + 32, I_B, M_B, st + 128);
    norm_k<0><<<512, cb, 0, stream>>>(I_B, M_B, proj, st + 128, flag, I_A, M_A);
    // L4
    layer_k<<<lg, cb, 0, stream>>>(I_A, M_A, w2d + 6912, afrag + 27648, biasf + 48, I_B, M_B, st + 192);
    // projection
    fproj1_k<<<256, cb, 0, stream>>>(I_B, I_XB, M_B, M_XB, st + 192, flag, d_out, P, PS, P0);
    fproj2_k<<<128, cb, 0, stream>>>(P, PS, P0, flag, d_out);
}